// Round 13
// baseline (478.530 us; speedup 1.0000x reference)
//
#include <hip/hip_runtime.h>

// ============================================================================
// MMAEKNN: MLP autoencoder fwd + rec_loss + KNN(15) loss, bf16 MFMA pipeline.
// R13: gram + GEMM1-filler converted to mfma_f32_32x32x16_bf16 (8 MFMA-issues
//      per K-step/wave instead of 16; 32x32 runs at the higher measured rate).
//      C/D map per m74/m101: col=lane&31, row=(reg&3)+8*(reg>>2)+4*(lane>>5).
//      d2s layout / selection / staging / thr_k / gemm_bt identical to R12.
// ============================================================================

typedef __attribute__((ext_vector_type(8))) short bf16x8;
typedef __attribute__((ext_vector_type(4))) float f32x4;
typedef __attribute__((ext_vector_type(16))) float f32x16;

#define DEVINL static __device__ __forceinline__

DEVINL unsigned short f2bf(float f){
  unsigned u = __float_as_uint(f);
  u += 0x7FFFu + ((u >> 16) & 1u);              // round-to-nearest-even
  return (unsigned short)(u >> 16);
}

DEVINL int med3i(int a, int b, int c){          // branchless sorted-insert step
  int d;
  asm("v_med3_i32 %0, %1, %2, %3" : "=v"(d) : "v"(a), "v"(b), "v"(c));
  return d;
}

DEVINL void gload16(const unsigned short* g, void* lds){
  __builtin_amdgcn_global_load_lds(
      (const __attribute__((address_space(1))) unsigned int*)g,
      (__attribute__((address_space(3))) unsigned int*)lds, 16, 0, 0);
}

// LDS-only barrier: waits own ds ops, syncs waves, does NOT drain vmcnt.
DEVINL void lds_barrier(){
  asm volatile("s_waitcnt lgkmcnt(0)" ::: "memory");
  __builtin_amdgcn_s_barrier();
  asm volatile("" ::: "memory");
}

#define NLISTS 39   // 8 row-scan (8 chunks, halves merged) + 31 col-scan

#define INS15(NAME, R0,R1,R2,R3,R4,R5,R6,R7,R8,R9,R10,R11,R12,R13,R14)  \
  auto NAME = [&](int v){                                               \
    if (v < R14){                                                       \
      R14 = med3i(v, R13, R14); R13 = med3i(v, R12, R13);               \
      R12 = med3i(v, R11, R12); R11 = med3i(v, R10, R11);               \
      R10 = med3i(v, R9 , R10); R9  = med3i(v, R8 , R9 );               \
      R8  = med3i(v, R7 , R8 ); R7  = med3i(v, R6 , R7 );               \
      R6  = med3i(v, R5 , R6 ); R5  = med3i(v, R4 , R5 );               \
      R4  = med3i(v, R3 , R4 ); R3  = med3i(v, R2 , R3 );               \
      R2  = med3i(v, R1 , R2 ); R1  = med3i(v, R0 , R1 );               \
      R0  = min(R0, v);                                                 \
    }                                                                   \
  }

// ---------------------------------------------------------------------------
// Fused: x f32->bf16 + row sum-of-squares (blocks 0..2047) and the 6 weight
// transposes f32 [K][N] -> bf16 [N][K] (blocks 2048..8255).
__global__ __launch_bounds__(256) void cvtT_k(const float* __restrict__ x,
    unsigned short* __restrict__ xb, float* __restrict__ xsq,
    const float* __restrict__ w0, const float* __restrict__ w1,
    const float* __restrict__ w2, const float* __restrict__ w3,
    const float* __restrict__ w4, const float* __restrict__ w5,
    unsigned short* __restrict__ t0, unsigned short* __restrict__ t1,
    unsigned short* __restrict__ t2, unsigned short* __restrict__ t3,
    unsigned short* __restrict__ t4, unsigned short* __restrict__ t5)
{
  __shared__ float t[32][33];
  const int tid = threadIdx.x;
  if (blockIdx.x >= 2048){
    int id = blockIdx.x - 2048;
    const float* w; unsigned short* wt; int K, N, loc;
    if      (id < 2048){ w = w0; wt = t0; K = 1024; N = 2048; loc = id; }
    else if (id < 3072){ w = w1; wt = t1; K = 2048; N = 512;  loc = id - 2048; }
    else if (id < 3104){ w = w2; wt = t2; K = 512;  N = 64;   loc = id - 3072; }
    else if (id < 3136){ w = w3; wt = t3; K = 64;   N = 512;  loc = id - 3104; }
    else if (id < 4160){ w = w4; wt = t4; K = 512;  N = 2048; loc = id - 3136; }
    else               { w = w5; wt = t5; K = 2048; N = 1024; loc = id - 4160; }
    const int ntn = N >> 5;
    const int n0 = (loc % ntn) << 5, k0 = (loc / ntn) << 5;
    const int tx = tid & 31, ty = tid >> 5;
    #pragma unroll
    for (int q = 0; q < 4; q++)
      t[ty + 8*q][tx] = w[(size_t)(k0 + ty + 8*q) * N + n0 + tx];
    __syncthreads();
    #pragma unroll
    for (int q = 0; q < 4; q++)
      wt[(size_t)(n0 + ty + 8*q) * K + k0 + tx] = f2bf(t[tx][ty + 8*q]);
    return;
  }
  const int lane = tid & 63, wv = tid >> 6;
  const int row = blockIdx.x * 4 + wv;
  const float4* px = (const float4*)(x + (size_t)row * 1024);
  ushort4* pb = (ushort4*)(xb + (size_t)row * 1024);
  float ss = 0.f;
  #pragma unroll
  for (int q = 0; q < 4; q++){
    float4 v = px[q * 64 + lane];
    ss += v.x*v.x + v.y*v.y + v.z*v.z + v.w*v.w;
    ushort4 o; o.x = f2bf(v.x); o.y = f2bf(v.y); o.z = f2bf(v.z); o.w = f2bf(v.w);
    pb[q * 64 + lane] = o;
  }
  #pragma unroll
  for (int o = 32; o; o >>= 1) ss += __shfl_xor(ss, o);
  if (!lane) xsq[row] = ss;
}

// ---------------------------------------------------------------------------
// thr_k: per-row filter threshold = 15th smallest bf16 d2 among the row's own
// 128-block neighbors (>= true 15th-NN d2 -> filtering v<=thr is safe).
__global__ __launch_bounds__(256, 2) void thr_k(
    const unsigned short* __restrict__ Xb, const float* __restrict__ xsq,
    int* __restrict__ thrI)
{
  __shared__ short As[128][32];
  __shared__ unsigned short d2s[128][130];
  const int tid = threadIdx.x, lane = tid & 63, wid = tid >> 6;
  const int wr = wid >> 1, wc = wid & 1;
  const int r16 = lane & 15, kg = lane >> 4;
  const int srow = lane >> 2, scol = (lane & 3) * 8;
  const float INF = __builtin_inff();
  const int b0 = blockIdx.x * 128;

  float xr[4][4];
  #pragma unroll
  for (int m = 0; m < 4; m++)
    #pragma unroll
    for (int r = 0; r < 4; r++)
      xr[m][r] = xsq[b0 + wr*64 + m*16 + kg*4 + r];

  const unsigned short* pa = Xb + (size_t)(b0 + wid*16 + srow) * 1024 + scol;
  short* ldsA0 = &As[wid*16][0];
  short* ldsA1 = &As[wid*16 + 64][0];

  f32x4 acc[4][4] = {};
  for (int k0 = 0; k0 < 1024; k0 += 32){
    __syncthreads();
    gload16(pa, ldsA0);
    gload16(pa + 65536, ldsA1);
    pa += 32;
    __syncthreads();
    bf16x8 af[4], bfr[4];
    #pragma unroll
    for (int m = 0; m < 4; m++) af[m]  = *(const bf16x8*)&As[wr*64 + m*16 + r16][kg*8];
    #pragma unroll
    for (int n = 0; n < 4; n++) bfr[n] = *(const bf16x8*)&As[wc*64 + n*16 + r16][kg*8];
    #pragma unroll
    for (int m = 0; m < 4; m++)
      #pragma unroll
      for (int n = 0; n < 4; n++)
        acc[m][n] = __builtin_amdgcn_mfma_f32_16x16x32_bf16(af[m], bfr[n], acc[m][n], 0, 0, 0);
  }
  float xc[4];
  #pragma unroll
  for (int n = 0; n < 4; n++) xc[n] = xsq[b0 + wc*64 + n*16 + r16];
  #pragma unroll
  for (int m = 0; m < 4; m++){
    #pragma unroll
    for (int n = 0; n < 4; n++){
      const int lc = wc*64 + n*16 + r16;
      #pragma unroll
      for (int r = 0; r < 4; r++){
        const int lr = wr*64 + m*16 + kg*4 + r;
        float v = xr[m][r] + xc[n] - 2.f * acc[m][n][r];
        if (lr == lc) v = INF;
        d2s[lr][lc] = f2bf(v);
      }
    }
  }
  __syncthreads();
  if (tid < 128){
    int r0,r1,r2,r3,r4,r5,r6,r7,r8,r9,r10,r11,r12,r13,r14;
    r0=r1=r2=r3=r4=r5=r6=r7=r8=r9=r10=r11=r12=r13=r14=0x7FFFFFFF;
    INS15(ins, r0,r1,r2,r3,r4,r5,r6,r7,r8,r9,r10,r11,r12,r13,r14);
    #pragma unroll 4
    for (int cc = 0; cc < 128; cc += 2){
      unsigned pv = *(const unsigned*)&d2s[tid][cc];
      ins((int)((pv << 16) | (unsigned)cc));
      ins((int)((pv & 0xFFFF0000u) | (unsigned)(cc + 1)));
    }
    thrI[b0 + tid] = (int)(((unsigned)r14 & 0xFFFF0000u) | 0xFFFFu);
  }
}

// ---------------------------------------------------------------------------
// NT GEMM: C[M,N] = A[M,K] @ Bt[N,K]^T (+bias, opt relu). bf16 in, f32 acc.
// Marching-pointer staging. OMODE 0: store bf16 C. 1: store bf16 + f32 C.
// 2: no store, per-block sum((C - Xref)^2) -> recPart[block].
// ---------------------------------------------------------------------------
template<int BM, int BN, int WM, int WN, bool RELU, int OMODE>
__global__ __launch_bounds__(256, 3) void gemm_bt(
    const unsigned short* __restrict__ A, const unsigned short* __restrict__ Bt,
    const float* __restrict__ bias, int M, int N, int K,
    unsigned short* __restrict__ Cb, float* __restrict__ Cf,
    const float* __restrict__ Xref, float* __restrict__ recPart)
{
  constexpr int FM = BM / (WM * 16), FN = BN / (WN * 16);
  constexpr int AIT = (BM/16 + 3) / 4, BIT = (BN/16 + 3) / 4;
  __shared__ short As[BM][32];
  __shared__ short Bs[BN][32];
  __shared__ float wsum[4];
  const int tid = threadIdx.x, lane = tid & 63, wid = tid >> 6;
  const int wr = wid / WN, wc = wid % WN;
  const int r16 = lane & 15, kg = lane >> 4;
  const int row0 = blockIdx.x * BM, col0 = blockIdx.y * BN;
  const int srow = lane >> 2, scol = (lane & 3) * 8;
  (void)M;
  const size_t chS = (size_t)64 * K;                 // ch += 4 -> 64 rows
  const unsigned short* pa = A  + (size_t)(row0 + wid*16 + srow) * K + scol;
  const unsigned short* pb = Bt + (size_t)(col0 + wid*16 + srow) * K + scol;
  f32x4 acc[FM][FN] = {};
  for (int k0 = 0; k0 < K; k0 += 32){
    __syncthreads();
    #pragma unroll
    for (int it = 0; it < AIT; ++it)
      if (it*4 + wid < BM/16)
        gload16(pa + it*chS, &As[(it*4 + wid)*16][0]);
    #pragma unroll
    for (int it = 0; it < BIT; ++it)
      if (it*4 + wid < BN/16)
        gload16(pb + it*chS, &Bs[(it*4 + wid)*16][0]);
    pa += 32; pb += 32;
    __syncthreads();
    bf16x8 af[FM], bfr[FN];
    #pragma unroll
    for (int m = 0; m < FM; m++) af[m]  = *(const bf16x8*)&As[wr*FM*16 + m*16 + r16][kg*8];
    #pragma unroll
    for (int n = 0; n < FN; n++) bfr[n] = *(const bf16x8*)&Bs[wc*FN*16 + n*16 + r16][kg*8];
    #pragma unroll
    for (int m = 0; m < FM; m++)
      #pragma unroll
      for (int n = 0; n < FN; n++)
        acc[m][n] = __builtin_amdgcn_mfma_f32_16x16x32_bf16(af[m], bfr[n], acc[m][n], 0, 0, 0);
  }
  float lsum = 0.f;
  #pragma unroll
  for (int m = 0; m < FM; m++){
    #pragma unroll
    for (int n = 0; n < FN; n++){
      const int gc = col0 + wc*FN*16 + n*16 + r16;
      const float bv = bias[gc];
      #pragma unroll
      for (int r = 0; r < 4; r++){
        const int gr = row0 + wr*FM*16 + m*16 + kg*4 + r;
        float v = acc[m][n][r] + bv;
        if (RELU) v = fmaxf(v, 0.f);
        if (OMODE == 2){
          float d = v - Xref[(size_t)gr * N + gc];
          lsum += d * d;
        } else {
          Cb[(size_t)gr * N + gc] = f2bf(v);
          if (OMODE == 1) Cf[(size_t)gr * N + gc] = v;
        }
      }
    }
  }
  if (OMODE == 2){
    #pragma unroll
    for (int o = 32; o; o >>= 1) lsum += __shfl_xor(lsum, o);
    if (!lane) wsum[wid] = lsum;
    __syncthreads();
    if (!tid) recPart[blockIdx.y * gridDim.x + blockIdx.x] =
        wsum[0] + wsum[1] + wsum[2] + wsum[3];
  }
}

// ---------------------------------------------------------------------------
// Fused: symmetric Gram + dual top-15 (blocks 0..511) + GEMM1 filler
// (blocks 512..1535). R13: 32x32x16 MFMA (2x2 tiles of 32x32 per wave);
// C/D map col=lane&31, row=(reg&3)+8*(reg>>2)+4*(lane>>5). Selection = R7/R10.
// ---------------------------------------------------------------------------
__global__ __launch_bounds__(256, 2) void gram_topk_k(
    const unsigned short* __restrict__ Xb, const float* __restrict__ xsq,
    const int* __restrict__ thrI, int* __restrict__ topP,
    const unsigned short* __restrict__ gBt, const float* __restrict__ gBias,
    unsigned short* __restrict__ gC)
{
  __shared__ short As[128][32];
  __shared__ short Bs[128][32];
  __shared__ unsigned short d2s[128][130];
  __shared__ int colL[128][15];
  __shared__ unsigned bkt[16][256];
  const int tid = threadIdx.x, lane = tid & 63, wid = tid >> 6;
  const int wr = wid >> 1, wc = wid & 1;
  const int l31 = lane & 31, lh = lane >> 5;      // 32x32 frag: row-in-tile, k-half
  const int srow = lane >> 2, scol = (lane & 3) * 8;

  short* ldsA0 = &As[wid*16][0];  short* ldsA1 = &As[wid*16 + 64][0];
  short* ldsB0 = &Bs[wid*16][0];  short* ldsB1 = &Bs[wid*16 + 64][0];
  auto stage2 = [&](const unsigned short* pa, const unsigned short* pb){
    gload16(pa,         ldsA0);
    gload16(pa + 65536, ldsA1);
    gload16(pb,         ldsB0);
    gload16(pb + 65536, ldsB1);
  };

  if (blockIdx.x >= 512){
    // ---------------- GEMM1 filler (32x32x16) ----------------
    const int gb = blockIdx.x - 512;
    const int row0 = (gb & 63) * 128, col0 = (gb >> 6) * 128;
    const unsigned short* pa = Xb  + (size_t)(row0 + wid*16 + srow) * 1024 + scol;
    const unsigned short* pb = gBt + (size_t)(col0 + wid*16 + srow) * 1024 + scol;
    f32x16 acc[2][2] = {};
    for (int k0 = 0; k0 < 1024; k0 += 32){
      __syncthreads();
      stage2(pa, pb);
      pa += 32; pb += 32;
      __syncthreads();
      bf16x8 a[2][2], b[2][2];
      #pragma unroll
      for (int tm = 0; tm < 2; ++tm){
        a[tm][0] = *(const bf16x8*)&As[wr*64 + tm*32 + l31][lh*8];
        a[tm][1] = *(const bf16x8*)&As[wr*64 + tm*32 + l31][16 + lh*8];
      }
      #pragma unroll
      for (int tn = 0; tn < 2; ++tn){
        b[tn][0] = *(const bf16x8*)&Bs[wc*64 + tn*32 + l31][lh*8];
        b[tn][1] = *(const bf16x8*)&Bs[wc*64 + tn*32 + l31][16 + lh*8];
      }
      #pragma unroll
      for (int h = 0; h < 2; ++h)
        #pragma unroll
        for (int tm = 0; tm < 2; ++tm)
          #pragma unroll
          for (int tn = 0; tn < 2; ++tn)
            acc[tm][tn] = __builtin_amdgcn_mfma_f32_32x32x16_bf16(
                a[tm][h], b[tn][h], acc[tm][tn], 0, 0, 0);
    }
    #pragma unroll
    for (int tn = 0; tn < 2; ++tn){
      const int gc = col0 + wc*64 + tn*32 + l31;
      const float bv = gBias[gc];
      #pragma unroll
      for (int tm = 0; tm < 2; ++tm){
        #pragma unroll
        for (int reg = 0; reg < 16; ++reg){
          const int gr = row0 + wr*64 + tm*32 + (reg&3) + 8*(reg>>2) + 4*lh;
          gC[(size_t)gr * 2048 + gc] = f2bf(fmaxf(acc[tm][tn][reg] + bv, 0.f));
        }
      }
    }
    return;
  }

  // ---------------- gram block ----------------
  const float INF = __builtin_inff();
  const int INFI = 0x7FFFFFFF;
  const int bi = blockIdx.x & 63;
  const int cl = blockIdx.x >> 6;          // 0..7
  const int row0 = bi * 128;
  const int ntt = (cl == 7) ? 5 : 4;
  const int selrow = tid & 127, half = tid >> 7, selc0 = half * 64;
  const int thrRI = thrI[row0 + selrow];

  const unsigned short* aB = Xb + (size_t)(row0 + wid*16 + srow) * 1024 + scol;

  int r0,r1,r2,r3,r4,r5,r6,r7,r8,r9,r10,r11,r12,r13,r14;
  r0=r1=r2=r3=r4=r5=r6=r7=r8=r9=r10=r11=r12=r13=r14=INFI;
  INS15(insR, r0,r1,r2,r3,r4,r5,r6,r7,r8,r9,r10,r11,r12,r13,r14);
  int c0,c1,c2,c3,c4,c5,c6,c7,c8,c9,c10,c11,c12,c13,c14;
  INS15(insC, c0,c1,c2,c3,c4,c5,c6,c7,c8,c9,c10,c11,c12,c13,c14);

  // per-thread row sums-of-squares for the 32 output rows this lane touches
  float xrq[2][16];
  #pragma unroll
  for (int tm = 0; tm < 2; ++tm)
    #pragma unroll
    for (int reg = 0; reg < 16; ++reg)
      xrq[tm][reg] = xsq[row0 + wr*64 + tm*32 + (reg&3) + 8*(reg>>2) + 4*lh];

  // prologue: stage tile 0 panel 0
  stage2(aB, Xb + (size_t)(((bi + cl*4) & 63) * 128 + wid*16 + srow) * 1024 + scol);

  for (int tt = 0; tt < ntt; ++tt){
    const int d = cl * 4 + tt;               // 0..32
    const int bj = (bi + d) & 63;
    const int j0 = bj * 128;
    const unsigned short* bB  = Xb + (size_t)(j0 + wid*16 + srow) * 1024 + scol;
    const unsigned short* bBn = Xb + (size_t)(((bi + d + 1) & 63) * 128 + wid*16 + srow) * 1024 + scol;
    const unsigned short* pa = aB;
    const unsigned short* pb = bB;
    f32x16 acc[2][2] = {};
    for (int k0 = 0; k0 < 1024; k0 += 32){
      __syncthreads();                       // staged panel ready (vmcnt drain)
      bf16x8 a[2][2], b[2][2];
      #pragma unroll
      for (int tm = 0; tm < 2; ++tm){
        a[tm][0] = *(const bf16x8*)&As[wr*64 + tm*32 + l31][lh*8];
        a[tm][1] = *(const bf16x8*)&As[wr*64 + tm*32 + l31][16 + lh*8];
      }
      #pragma unroll
      for (int tn = 0; tn < 2; ++tn){
        b[tn][0] = *(const bf16x8*)&Bs[wc*64 + tn*32 + l31][lh*8];
        b[tn][1] = *(const bf16x8*)&Bs[wc*64 + tn*32 + l31][16 + lh*8];
      }
      __syncthreads();                       // frag reads complete
      if (k0 + 32 < 1024){ pa += 32; pb += 32; stage2(pa, pb); }
      else if (tt + 1 < ntt) stage2(aB, bBn);
      #pragma unroll
      for (int h = 0; h < 2; ++h)
        #pragma unroll
        for (int tm = 0; tm < 2; ++tm)
          #pragma unroll
          for (int tn = 0; tn < 2; ++tn)
            acc[tm][tn] = __builtin_amdgcn_mfma_f32_32x32x16_bf16(
                a[tm][h], b[tn][h], acc[tm][tn], 0, 0, 0);
    }
    // d^2 tile -> bf16 LDS (diag -> +inf)
    float xcq[2];
    #pragma unroll
    for (int tn = 0; tn < 2; ++tn) xcq[tn] = xsq[j0 + wc*64 + tn*32 + l31];
    #pragma unroll
    for (int tm = 0; tm < 2; ++tm){
      #pragma unroll
      for (int tn = 0; tn < 2; ++tn){
        const int lc = wc*64 + tn*32 + l31;
        #pragma unroll
        for (int reg = 0; reg < 16; ++reg){
          const int lr = wr*64 + tm*32 + (reg&3) + 8*(reg>>2) + 4*lh;
          float v = xrq[tm][reg] + xcq[tn] - 2.f * acc[tm][tn][reg];
          if (row0 + lr == j0 + lc) v = INF;
          d2s[lr][lc] = f2bf(v);
        }
      }
    }
    lds_barrier();                           // d2s ready (prefetch stays in flight)

    // row-scan phase A: thr-passers -> private bucket (rare overflow: direct)
    {
      int cnt = 0;
      const int jg0 = j0 + selc0;
      #pragma unroll 4
      for (int cc = 0; cc < 64; cc += 2){
        unsigned pv = *(const unsigned*)&d2s[selrow][selc0 + cc];
        int p0 = (int)((pv << 16) | (unsigned)(jg0 + cc));
        int p1 = (int)((pv & 0xFFFF0000u) | (unsigned)(jg0 + cc + 1));
        if (p0 <= thrRI){
          if (cnt < 16){ bkt[cnt][tid] = (unsigned)p0; ++cnt; } else insR(p0);
        }
        if (p1 <= thrRI){
          if (cnt < 16){ bkt[cnt][tid] = (unsigned)p1; ++cnt; } else insR(p1);
        }
      }
      // phase B: drain bucket (wave cost = max-lane count, not 64 steps)
      for (int q = 0; q < cnt; ++q) insR((int)bkt[q][tid]);
    }

    // col-scan (rows of bj), d in [1..31]
    const bool doCol = (d >= 1) && (d <= 31);
    if (doCol){
      c0=c1=c2=c3=c4=c5=c6=c7=c8=c9=c10=c11=c12=c13=c14=INFI;
      const int thrCI = thrI[j0 + selrow];
      const int rbase = row0 + selc0;
      int cnt = 0;
      #pragma unroll 4
      for (int rr = 0; rr < 64; ++rr){
        unsigned v = d2s[selc0 + rr][selrow];
        int pk = (int)((v << 16) | (unsigned)(rbase + rr));
        if (pk <= thrCI){
          if (cnt < 16){ bkt[cnt][tid] = (unsigned)pk; ++cnt; } else insC(pk);
        }
      }
      for (int q = 0; q < cnt; ++q) insC((int)bkt[q][tid]);
      if (half){
        colL[selrow][0]=c0;  colL[selrow][1]=c1;  colL[selrow][2]=c2;
        colL[selrow][3]=c3;  colL[selrow][4]=c4;  colL[selrow][5]=c5;
        colL[selrow][6]=c6;  colL[selrow][7]=c7;  colL[selrow][8]=c8;
        colL[selrow][9]=c9;  colL[selrow][10]=c10; colL[selrow][11]=c11;
        colL[selrow][12]=c12; colL[selrow][13]=c13; colL[selrow][14]=c14;
      }
    }
    lds_barrier();                           // colL ready / d2s reads done
    if (doCol && !half){
      #pragma unroll 1
      for (int q = 0; q < 15; ++q){
        int v = colL[selrow][q];
        if (v >= c14) break;
        insC(v);
      }
      int* dst = topP + ((size_t)(j0 + selrow) * NLISTS + (8 + d - 1)) * 15;
      dst[0]=c0;  dst[1]=c1;  dst[2]=c2;  dst[3]=c3;  dst[4]=c4;
      dst[5]=c5;  dst[6]=c6;  dst[7]=c7;  dst[8]=c8;  dst[9]=c9;
      dst[10]=c10; dst[11]=c11; dst[12]=c12; dst[13]=c13; dst[14]=c14;
    }
  }
  // merge row-scan halves in LDS -> one list per row per chunk (slot cl)
  lds_barrier();
  if (half){
    colL[selrow][0]=r0;  colL[selrow][1]=r1;  colL[selrow][2]=r2;
    colL[selrow][3]=r3;  colL[selrow][4]=r4;  colL[selrow][5]=r5;
    colL[selrow][6]=r6;  colL[selrow][7]=r7;  colL[selrow][8]=r8;
    colL[selrow][9]=r9;  colL[selrow][10]=r10; colL[selrow][11]=r11;
    colL[selrow][12]=r12; colL[selrow][13]=r13; colL[selrow][14]=r14;
  }
  lds_barrier();
  if (!half){
    #pragma unroll 1
    for (int q = 0; q < 15; ++q){
      int v = colL[selrow][q];
      if (v >= r14) break;
      insR(v);
    }
    int* dst = topP + ((size_t)(row0 + selrow) * NLISTS + cl) * 15;
    dst[0]=r0;  dst[1]=r1;  dst[2]=r2;  dst[3]=r3;  dst[4]=r4;
    dst[5]=r5;  dst[6]=r6;  dst[7]=r7;  dst[8]=r8;  dst[9]=r9;
    dst[10]=r10; dst[11]=r11; dst[12]=r12; dst[13]=r13; dst[14]=r14;
  }
}

// merge 39 partial 15-lists (585 candidates, disjoint j) -> final 15 per row.
// Also per-block max of 15th-NN d2 (x_max) -> xpart[block].
__global__ __launch_bounds__(256) void merge_topk_k(const int* __restrict__ topP,
    int* __restrict__ knn, float* __restrict__ d2k, float* __restrict__ xpart)
{
  __shared__ float wmax[4];
  const int lane = threadIdx.x & 63, wid = threadIdx.x >> 6;
  const int row = blockIdx.x * 4 + wid;
  const int* tp = topP + (size_t)row * (NLISTS * 15);
  const int INFI = 0x7FFFFFFF;
  int c0 = tp[lane];
  int c1 = tp[lane + 64];
  int c2 = tp[lane + 128];
  int c3 = tp[lane + 192];
  int c4 = tp[lane + 256];
  int c5 = tp[lane + 320];
  int c6 = tp[lane + 384];
  int c7 = tp[lane + 448];
  int c8 = tp[lane + 512];
  int c9 = (lane < 9) ? tp[lane + 576] : INFI;
  float last = 0.f;
  for (int it = 0; it < 15; ++it){
    int m = min(min(min(c0, c1), min(c2, c3)), min(min(c4, c5), min(c6, c7)));
    m = min(m, min(c8, c9));
    #pragma unroll
    for (int o = 32; o; o >>= 1) m = min(m, __shfl_xor(m, o));
    if (!lane){
      knn[row * 15 + it] = m & 0xFFFF;
      float f = __uint_as_float((unsigned)m & 0xFFFF0000u);
      d2k[row * 15 + it] = f;
      last = f;
    }
    c0 = (c0 == m) ? INFI : c0;   c1 = (c1 == m) ? INFI : c1;
    c2 = (c2 == m) ? INFI : c2;   c3 = (c3 == m) ? INFI : c3;
    c4 = (c4 == m) ? INFI : c4;   c5 = (c5 == m) ? INFI : c5;
    c6 = (c6 == m) ? INFI : c6;   c7 = (c7 == m) ? INFI : c7;
    c8 = (c8 == m) ? INFI : c8;   c9 = (c9 == m) ? INFI : c9;
  }
  if (!lane) wmax[wid] = last;
  __syncthreads();
  if (!threadIdx.x)
    xpart[blockIdx.x] = fmaxf(fmaxf(wmax[0], wmax[1]), fmaxf(wmax[2], wmax[3]));
}

// ---------------------------------------------------------------------------
// Edge-based loss sums over the 122880 directed knn edges. For edge (i,j):
// mult = 1 + [i in knn[j]]; weight w = 2/mult. Equals the masked-pair mean.
__global__ __launch_bounds__(256) void pair_sums_k(
    const float* __restrict__ z, const int* __restrict__ knn,
    const float* __restrict__ d2k,
    float* __restrict__ zzP, float* __restrict__ zxP, float* __restrict__ xxP,
    float* __restrict__ zmP, float* __restrict__ cntP)
{
  __shared__ float red[4][5];
  const int lane = threadIdx.x & 63, wid = threadIdx.x >> 6;
  float szz = 0.f, szx = 0.f, sxx = 0.f, mz = 0.f, scnt = 0.f;
  for (int p = blockIdx.x * 4 + wid; p < 122880; p += gridDim.x * 4){
    const int i = p / 15;
    const int j = knn[p];
    const float dx2 = d2k[p];
    float dd = z[(size_t)i * 64 + lane] - z[(size_t)j * 64 + lane];
    float s = dd * dd;
    #pragma unroll
    for (int o = 32; o; o >>= 1) s += __shfl_xor(s, o);
    int kj = knn[j * 15 + min(lane, 14)];
    unsigned long long m2 = __ballot(lane < 15 && kj == i);
    const float w = m2 ? 1.f : 2.f;          // 2/mult
    float dz = sqrtf(s), dx = sqrtf(dx2);
    szz += w * s;
    szx += w * dz * dx;
    sxx += w * dx2;
    scnt += w;
    mz = fmaxf(mz, dz);
  }
  if (!lane){
    red[wid][0] = szz; red[wid][1] = szx; red[wid][2] = sxx;
    red[wid][3] = mz;  red[wid][4] = scnt;
  }
  __syncthreads();
  if (!threadIdx.x){
    float a = 0.f, b = 0.f, c = 0.f, m = 0.f, n = 0.f;
    #pragma unroll
    for (int w = 0; w < 4; w++){
      a += red[w][0]; b += red[w][1]; c += red[w][2];
      m = fmaxf(m, red[w][3]); n += red[w][4];
    }
    zzP[blockIdx.x] = a; zxP[blockIdx.x] = b; xxP[blockIdx.x] = c;
    zmP[blockIdx.x] = m; cntP[blockIdx.x] = n;
  }
}

// single block: reduce all partials, compute losses, write outputs.
__global__ __launch_bounds__(256) void final_reduce_k(
    const float* __restrict__ recPart, const float* __restrict__ xpart,
    const float* __restrict__ zzP, const float* __restrict__ zxP,
    const float* __restrict__ xxP, const float* __restrict__ zmP,
    const float* __restrict__ cntP, float* __restrict__ out)
{
  __shared__ float rd[4][7];
  const int t = threadIdx.x, lane = t & 63, wid = t >> 6;
  float rec = 0.f, xm = 0.f, zz = 0.f, zx = 0.f, xx = 0.f, zm = 0.f, cnt = 0.f;
  for (int i = t; i < 1024; i += 256) rec += recPart[i];
  for (int i = t; i < 2048; i += 256) xm = fmaxf(xm, xpart[i]);
  for (int i = t; i < 1920; i += 256){
    zz += zzP[i]; zx += zxP[i]; xx += xxP[i]; cnt += cntP[i];
    zm = fmaxf(zm, zmP[i]);
  }
  #pragma unroll
  for (int o = 32; o; o >>= 1){
    rec += __shfl_xor(rec, o); zz += __shfl_xor(zz, o);
    zx  += __shfl_xor(zx, o);  xx += __shfl_xor(xx, o);
    cnt += __shfl_xor(cnt, o);
    xm = fmaxf(xm, __shfl_xor(xm, o));
    zm = fmaxf(zm, __shfl_xor(zm, o));
  }
  if (!lane){
    rd[wid][0]=rec; rd[wid][1]=zz; rd[wid][2]=zx; rd[wid][3]=xx;
    rd[wid][4]=xm;  rd[wid][5]=zm; rd[wid][6]=cnt;
  }
  __syncthreads();
  if (!t){
    rec = rd[0][0]+rd[1][0]+rd[2][0]+rd[3][0];
    zz  = rd[0][1]+rd[1][1]+rd[2][1]+rd[3][1];
    zx  = rd[0][2]+rd[1][2]+rd[2][2]+rd[3][2];
    xx  = rd[0][3]+rd[1][3]+rd[2][3]+rd[3][3];
    xm  = fmaxf(fmaxf(rd[0][4],rd[1][4]), fmaxf(rd[2][4],rd[3][4]));
    zm  = fmaxf(fmaxf(rd[0][5],rd[1][5]), fmaxf(rd[2][5],rd[3][5]));
    cnt = rd[0][6]+rd[1][6]+rd[2][6]+rd[3][6];
    rec *= 1.0f / (8192.0f * 1024.0f);
    float xmax = sqrtf(xm);
    float rx = 1.0f / (xmax + 1e-8f), rz = 1.0f / (zm + 1e-8f);
    float knn = (zz * rz * rz - 2.0f * zx * rz * rx + xx * rx * rx) / cnt;
    out[0] = rec + knn;                 // total
    out[1 + 8192 * 64]     = rec;       // rec_loss
    out[1 + 8192 * 64 + 1] = knn;       // knn_loss
  }
}

// ===========================================================================
extern "C" void kernel_launch(void* const* d_in, const int* in_sizes, int n_in,
                              void* d_out, int out_size, void* d_ws, size_t ws_size,
                              hipStream_t stream)
{
  (void)in_sizes; (void)n_in; (void)out_size;
  const float* x    = (const float*)d_in[0];
  const float* w_e0 = (const float*)d_in[1];  const float* b_e0 = (const float*)d_in[2];
  const float* w_e1 = (const float*)d_in[3];  const float* b_e1 = (const float*)d_in[4];
  const float* w_e2 = (const float*)d_in[5];  const float* b_e2 = (const float*)d_in[6];
  const float* w_d0 = (const float*)d_in[7];  const float* b_d0 = (const float*)d_in[8];
  const float* w_d1 = (const float*)d_in[9];  const float* b_d1 = (const float*)d_in[10];
  const float* w_d2 = (const float*)d_in[11]; const float* b_d2 = (const float*)d_in[12];
  float* out = (float*)d_out;

  char* ws = (char*)d_ws;
  size_t off = 0;
  auto alloc = [&](size_t bytes) -> void* {
    void* p = ws + off;
    off += (bytes + 255) & ~(size_t)255;
    return p;
  };
  unsigned short* xb   = (unsigned short*)alloc(8192ull * 1024 * 2);
  unsigned short* wte0 = (unsigned short*)alloc(2048ull * 1024 * 2);
  unsigned short* wte1 = (unsigned short*)alloc(512ull  * 2048 * 2);
  unsigned short* wte2 = (unsigned short*)alloc(64ull   * 512  * 2);
  unsigned short* wtd0 = (unsigned short*)alloc(512ull  * 64   * 2);
  unsigned short* wtd1 = (unsigned short*)alloc(2048ull * 512  * 2);
  unsigned short* wtd2 = (unsigned short*)alloc(1024ull * 2048 * 2);
  unsigned short* bufA = (unsigned short*)alloc(8192ull * 2048 * 2);   // H1 / H4
  unsigned short* bufB = (unsigned short*)alloc(8192ull * 512  * 2);   // H2 / H3
  unsigned short* zb   = (unsigned short*)alloc(8192ull * 64   * 2);
  int*   topP   = (int*)  alloc(8192ull * NLISTS * 15 * 4);            // 19.2MB
  float* xsq    = (float*)alloc(8192 * 4);
  int*   thrI   = (int*)  alloc(8192 * 4);
  int*   knn    = (int*)  alloc(8192ull * 15 * 4);
  float* d2k    = (float*)alloc(8192ull * 15 * 4);
  float* xpart  = (float*)alloc(2048 * 4);
  float* zzP    = (float*)alloc(1920 * 4);
  float* zxP    = (float*)alloc(1920 * 4);
  float* xxP    = (float*)alloc(1920 * 4);
  float* zmP    = (float*)alloc(1920 * 4);
  float* cntP   = (float*)alloc(1920 * 4);
  float* recPart= (float*)alloc(1024 * 4);
  if (off > ws_size) return;   // fail loudly (poisoned output) rather than corrupt

  // --- conversions + weight transposes (one launch) ---
  cvtT_k<<<8256, 256, 0, stream>>>(x, xb, xsq,
      w_e0, w_e1, w_e2, w_d0, w_d1, w_d2, wte0, wte1, wte2, wtd0, wtd1, wtd2);

  // --- per-row selection thresholds (diag-block 15th-NN) ---
  thr_k<<<64, 256, 0, stream>>>(xb, xsq, thrI);

  // --- fused: gram+top15 (0..511) + GEMM1 tail-filler (512..1535) ---
  gram_topk_k<<<1536, 256, 0, stream>>>(xb, xsq, thrI, topP, wte0, b_e0, bufA);
  merge_topk_k<<<2048, 256, 0, stream>>>(topP, knn, d2k, xpart);

  // --- rest of MLP ---
  gemm_bt<128, 64,2,2,true ,0><<<dim3(64, 8), 256, 0, stream>>>(bufA, wte1, b_e1, 8192,  512, 2048, bufB, nullptr, nullptr, nullptr);
  gemm_bt< 32, 64,2,2,false,1><<<dim3(256,1), 256, 0, stream>>>(bufB, wte2, b_e2, 8192,   64,  512, zb,   out + 1, nullptr, nullptr);
  gemm_bt<128, 64,2,2,true ,0><<<dim3(64, 8), 256, 0, stream>>>(zb,   wtd0, b_d0, 8192,  512,   64, bufB, nullptr, nullptr, nullptr);
  gemm_bt<128,128,2,2,true ,0><<<dim3(64,16), 256, 0, stream>>>(bufB, wtd1, b_d1, 8192, 2048,  512, bufA, nullptr, nullptr, nullptr);
  gemm_bt< 64,128,2,2,false,2><<<dim3(128,8), 256, 0, stream>>>(bufA, wtd2, b_d2, 8192, 1024, 2048, nullptr, nullptr, x, recPart);

  // --- KNN loss tail (edge-based) ---
  pair_sums_k<<<1920, 256, 0, stream>>>(out + 1, knn, d2k, zzP, zxP, xxP, zmP, cntP);
  final_reduce_k<<<1, 256, 0, stream>>>(recPart, xpart, zzP, zxP, xxP, zmP, cntP, out);
}

// Round 14
// 402.621 us; speedup vs baseline: 1.1885x; 1.1885x over previous
//
#include <hip/hip_runtime.h>

// ============================================================================
// MMAEKNN: MLP autoencoder fwd + rec_loss + KNN(15) loss, bf16 MFMA pipeline.
// R14: revert to R12 (best verified, 402.9us). R13's 32x32 MFMA regressed:
//      bank conflicts 1.39e7 -> 3.85e7 (32-lane same-column frag reads +
//      16-reg epilogue scatter), WRITE +44MB, VGPR 128. The 16x16 layout's
//      frag reads / d2s writes are conflict-benign; keep them.
//      Structure: cyclic symmetric gram + thr-filter/bucket top-15 + GEMM1
//      tail-filler (fused), marching-pointer staging, edge-based KNN tail.
// ============================================================================

typedef __attribute__((ext_vector_type(8))) short bf16x8;
typedef __attribute__((ext_vector_type(4))) float f32x4;

#define DEVINL static __device__ __forceinline__

DEVINL unsigned short f2bf(float f){
  unsigned u = __float_as_uint(f);
  u += 0x7FFFu + ((u >> 16) & 1u);              // round-to-nearest-even
  return (unsigned short)(u >> 16);
}

DEVINL int med3i(int a, int b, int c){          // branchless sorted-insert step
  int d;
  asm("v_med3_i32 %0, %1, %2, %3" : "=v"(d) : "v"(a), "v"(b), "v"(c));
  return d;
}

DEVINL void gload16(const unsigned short* g, void* lds){
  __builtin_amdgcn_global_load_lds(
      (const __attribute__((address_space(1))) unsigned int*)g,
      (__attribute__((address_space(3))) unsigned int*)lds, 16, 0, 0);
}

// LDS-only barrier: waits own ds ops, syncs waves, does NOT drain vmcnt.
DEVINL void lds_barrier(){
  asm volatile("s_waitcnt lgkmcnt(0)" ::: "memory");
  __builtin_amdgcn_s_barrier();
  asm volatile("" ::: "memory");
}

#define NLISTS 39   // 8 row-scan (8 chunks, halves merged) + 31 col-scan

#define INS15(NAME, R0,R1,R2,R3,R4,R5,R6,R7,R8,R9,R10,R11,R12,R13,R14)  \
  auto NAME = [&](int v){                                               \
    if (v < R14){                                                       \
      R14 = med3i(v, R13, R14); R13 = med3i(v, R12, R13);               \
      R12 = med3i(v, R11, R12); R11 = med3i(v, R10, R11);               \
      R10 = med3i(v, R9 , R10); R9  = med3i(v, R8 , R9 );               \
      R8  = med3i(v, R7 , R8 ); R7  = med3i(v, R6 , R7 );               \
      R6  = med3i(v, R5 , R6 ); R5  = med3i(v, R4 , R5 );               \
      R4  = med3i(v, R3 , R4 ); R3  = med3i(v, R2 , R3 );               \
      R2  = med3i(v, R1 , R2 ); R1  = med3i(v, R0 , R1 );               \
      R0  = min(R0, v);                                                 \
    }                                                                   \
  }

// ---------------------------------------------------------------------------
// Fused: x f32->bf16 + row sum-of-squares (blocks 0..2047) and the 6 weight
// transposes f32 [K][N] -> bf16 [N][K] (blocks 2048..8255).
__global__ __launch_bounds__(256) void cvtT_k(const float* __restrict__ x,
    unsigned short* __restrict__ xb, float* __restrict__ xsq,
    const float* __restrict__ w0, const float* __restrict__ w1,
    const float* __restrict__ w2, const float* __restrict__ w3,
    const float* __restrict__ w4, const float* __restrict__ w5,
    unsigned short* __restrict__ t0, unsigned short* __restrict__ t1,
    unsigned short* __restrict__ t2, unsigned short* __restrict__ t3,
    unsigned short* __restrict__ t4, unsigned short* __restrict__ t5)
{
  __shared__ float t[32][33];
  const int tid = threadIdx.x;
  if (blockIdx.x >= 2048){
    int id = blockIdx.x - 2048;
    const float* w; unsigned short* wt; int K, N, loc;
    if      (id < 2048){ w = w0; wt = t0; K = 1024; N = 2048; loc = id; }
    else if (id < 3072){ w = w1; wt = t1; K = 2048; N = 512;  loc = id - 2048; }
    else if (id < 3104){ w = w2; wt = t2; K = 512;  N = 64;   loc = id - 3072; }
    else if (id < 3136){ w = w3; wt = t3; K = 64;   N = 512;  loc = id - 3104; }
    else if (id < 4160){ w = w4; wt = t4; K = 512;  N = 2048; loc = id - 3136; }
    else               { w = w5; wt = t5; K = 2048; N = 1024; loc = id - 4160; }
    const int ntn = N >> 5;
    const int n0 = (loc % ntn) << 5, k0 = (loc / ntn) << 5;
    const int tx = tid & 31, ty = tid >> 5;
    #pragma unroll
    for (int q = 0; q < 4; q++)
      t[ty + 8*q][tx] = w[(size_t)(k0 + ty + 8*q) * N + n0 + tx];
    __syncthreads();
    #pragma unroll
    for (int q = 0; q < 4; q++)
      wt[(size_t)(n0 + ty + 8*q) * K + k0 + tx] = f2bf(t[tx][ty + 8*q]);
    return;
  }
  const int lane = tid & 63, wv = tid >> 6;
  const int row = blockIdx.x * 4 + wv;
  const float4* px = (const float4*)(x + (size_t)row * 1024);
  ushort4* pb = (ushort4*)(xb + (size_t)row * 1024);
  float ss = 0.f;
  #pragma unroll
  for (int q = 0; q < 4; q++){
    float4 v = px[q * 64 + lane];
    ss += v.x*v.x + v.y*v.y + v.z*v.z + v.w*v.w;
    ushort4 o; o.x = f2bf(v.x); o.y = f2bf(v.y); o.z = f2bf(v.z); o.w = f2bf(v.w);
    pb[q * 64 + lane] = o;
  }
  #pragma unroll
  for (int o = 32; o; o >>= 1) ss += __shfl_xor(ss, o);
  if (!lane) xsq[row] = ss;
}

// ---------------------------------------------------------------------------
// thr_k: per-row filter threshold = 15th smallest bf16 d2 among the row's own
// 128-block neighbors (>= true 15th-NN d2 -> filtering v<=thr is safe).
__global__ __launch_bounds__(256, 2) void thr_k(
    const unsigned short* __restrict__ Xb, const float* __restrict__ xsq,
    int* __restrict__ thrI)
{
  __shared__ short As[128][32];
  __shared__ unsigned short d2s[128][130];
  const int tid = threadIdx.x, lane = tid & 63, wid = tid >> 6;
  const int wr = wid >> 1, wc = wid & 1;
  const int r16 = lane & 15, kg = lane >> 4;
  const int srow = lane >> 2, scol = (lane & 3) * 8;
  const float INF = __builtin_inff();
  const int b0 = blockIdx.x * 128;

  float xr[4][4];
  #pragma unroll
  for (int m = 0; m < 4; m++)
    #pragma unroll
    for (int r = 0; r < 4; r++)
      xr[m][r] = xsq[b0 + wr*64 + m*16 + kg*4 + r];

  const unsigned short* pa = Xb + (size_t)(b0 + wid*16 + srow) * 1024 + scol;
  short* ldsA0 = &As[wid*16][0];
  short* ldsA1 = &As[wid*16 + 64][0];

  f32x4 acc[4][4] = {};
  for (int k0 = 0; k0 < 1024; k0 += 32){
    __syncthreads();
    gload16(pa, ldsA0);
    gload16(pa + 65536, ldsA1);
    pa += 32;
    __syncthreads();
    bf16x8 af[4], bfr[4];
    #pragma unroll
    for (int m = 0; m < 4; m++) af[m]  = *(const bf16x8*)&As[wr*64 + m*16 + r16][kg*8];
    #pragma unroll
    for (int n = 0; n < 4; n++) bfr[n] = *(const bf16x8*)&As[wc*64 + n*16 + r16][kg*8];
    #pragma unroll
    for (int m = 0; m < 4; m++)
      #pragma unroll
      for (int n = 0; n < 4; n++)
        acc[m][n] = __builtin_amdgcn_mfma_f32_16x16x32_bf16(af[m], bfr[n], acc[m][n], 0, 0, 0);
  }
  float xc[4];
  #pragma unroll
  for (int n = 0; n < 4; n++) xc[n] = xsq[b0 + wc*64 + n*16 + r16];
  #pragma unroll
  for (int m = 0; m < 4; m++){
    #pragma unroll
    for (int n = 0; n < 4; n++){
      const int lc = wc*64 + n*16 + r16;
      #pragma unroll
      for (int r = 0; r < 4; r++){
        const int lr = wr*64 + m*16 + kg*4 + r;
        float v = xr[m][r] + xc[n] - 2.f * acc[m][n][r];
        if (lr == lc) v = INF;
        d2s[lr][lc] = f2bf(v);
      }
    }
  }
  __syncthreads();
  if (tid < 128){
    int r0,r1,r2,r3,r4,r5,r6,r7,r8,r9,r10,r11,r12,r13,r14;
    r0=r1=r2=r3=r4=r5=r6=r7=r8=r9=r10=r11=r12=r13=r14=0x7FFFFFFF;
    INS15(ins, r0,r1,r2,r3,r4,r5,r6,r7,r8,r9,r10,r11,r12,r13,r14);
    #pragma unroll 4
    for (int cc = 0; cc < 128; cc += 2){
      unsigned pv = *(const unsigned*)&d2s[tid][cc];
      ins((int)((pv << 16) | (unsigned)cc));
      ins((int)((pv & 0xFFFF0000u) | (unsigned)(cc + 1)));
    }
    thrI[b0 + tid] = (int)(((unsigned)r14 & 0xFFFF0000u) | 0xFFFFu);
  }
}

// ---------------------------------------------------------------------------
// NT GEMM: C[M,N] = A[M,K] @ Bt[N,K]^T (+bias, opt relu). bf16 in, f32 acc.
// Marching-pointer staging. OMODE 0: store bf16 C. 1: store bf16 + f32 C.
// 2: no store, per-block sum((C - Xref)^2) -> recPart[block].
// ---------------------------------------------------------------------------
template<int BM, int BN, int WM, int WN, bool RELU, int OMODE>
__global__ __launch_bounds__(256, 3) void gemm_bt(
    const unsigned short* __restrict__ A, const unsigned short* __restrict__ Bt,
    const float* __restrict__ bias, int M, int N, int K,
    unsigned short* __restrict__ Cb, float* __restrict__ Cf,
    const float* __restrict__ Xref, float* __restrict__ recPart)
{
  constexpr int FM = BM / (WM * 16), FN = BN / (WN * 16);
  constexpr int AIT = (BM/16 + 3) / 4, BIT = (BN/16 + 3) / 4;
  __shared__ short As[BM][32];
  __shared__ short Bs[BN][32];
  __shared__ float wsum[4];
  const int tid = threadIdx.x, lane = tid & 63, wid = tid >> 6;
  const int wr = wid / WN, wc = wid % WN;
  const int r16 = lane & 15, kg = lane >> 4;
  const int row0 = blockIdx.x * BM, col0 = blockIdx.y * BN;
  const int srow = lane >> 2, scol = (lane & 3) * 8;
  (void)M;
  const size_t chS = (size_t)64 * K;                 // ch += 4 -> 64 rows
  const unsigned short* pa = A  + (size_t)(row0 + wid*16 + srow) * K + scol;
  const unsigned short* pb = Bt + (size_t)(col0 + wid*16 + srow) * K + scol;
  f32x4 acc[FM][FN] = {};
  for (int k0 = 0; k0 < K; k0 += 32){
    __syncthreads();
    #pragma unroll
    for (int it = 0; it < AIT; ++it)
      if (it*4 + wid < BM/16)
        gload16(pa + it*chS, &As[(it*4 + wid)*16][0]);
    #pragma unroll
    for (int it = 0; it < BIT; ++it)
      if (it*4 + wid < BN/16)
        gload16(pb + it*chS, &Bs[(it*4 + wid)*16][0]);
    pa += 32; pb += 32;
    __syncthreads();
    bf16x8 af[FM], bfr[FN];
    #pragma unroll
    for (int m = 0; m < FM; m++) af[m]  = *(const bf16x8*)&As[wr*FM*16 + m*16 + r16][kg*8];
    #pragma unroll
    for (int n = 0; n < FN; n++) bfr[n] = *(const bf16x8*)&Bs[wc*FN*16 + n*16 + r16][kg*8];
    #pragma unroll
    for (int m = 0; m < FM; m++)
      #pragma unroll
      for (int n = 0; n < FN; n++)
        acc[m][n] = __builtin_amdgcn_mfma_f32_16x16x32_bf16(af[m], bfr[n], acc[m][n], 0, 0, 0);
  }
  float lsum = 0.f;
  #pragma unroll
  for (int m = 0; m < FM; m++){
    #pragma unroll
    for (int n = 0; n < FN; n++){
      const int gc = col0 + wc*FN*16 + n*16 + r16;
      const float bv = bias[gc];
      #pragma unroll
      for (int r = 0; r < 4; r++){
        const int gr = row0 + wr*FM*16 + m*16 + kg*4 + r;
        float v = acc[m][n][r] + bv;
        if (RELU) v = fmaxf(v, 0.f);
        if (OMODE == 2){
          float d = v - Xref[(size_t)gr * N + gc];
          lsum += d * d;
        } else {
          Cb[(size_t)gr * N + gc] = f2bf(v);
          if (OMODE == 1) Cf[(size_t)gr * N + gc] = v;
        }
      }
    }
  }
  if (OMODE == 2){
    #pragma unroll
    for (int o = 32; o; o >>= 1) lsum += __shfl_xor(lsum, o);
    if (!lane) wsum[wid] = lsum;
    __syncthreads();
    if (!tid) recPart[blockIdx.y * gridDim.x + blockIdx.x] =
        wsum[0] + wsum[1] + wsum[2] + wsum[3];
  }
}

// ---------------------------------------------------------------------------
// Fused: symmetric Gram + dual top-15 (blocks 0..511, balanced-cyclic R4 +
// pipelined staging R5 + thr-filter/bucket selection R7 + marching pointers
// R10) and GEMM1 filler (blocks 512..1535): bufA = relu(xb @ wte0^T + b_e0).
// ---------------------------------------------------------------------------
__global__ __launch_bounds__(256, 2) void gram_topk_k(
    const unsigned short* __restrict__ Xb, const float* __restrict__ xsq,
    const int* __restrict__ thrI, int* __restrict__ topP,
    const unsigned short* __restrict__ gBt, const float* __restrict__ gBias,
    unsigned short* __restrict__ gC)
{
  __shared__ short As[128][32];
  __shared__ short Bs[128][32];
  __shared__ unsigned short d2s[128][130];
  __shared__ int colL[128][15];
  __shared__ unsigned bkt[16][256];
  const int tid = threadIdx.x, lane = tid & 63, wid = tid >> 6;
  const int wr = wid >> 1, wc = wid & 1;
  const int r16 = lane & 15, kg = lane >> 4;
  const int srow = lane >> 2, scol = (lane & 3) * 8;

  short* ldsA0 = &As[wid*16][0];  short* ldsA1 = &As[wid*16 + 64][0];
  short* ldsB0 = &Bs[wid*16][0];  short* ldsB1 = &Bs[wid*16 + 64][0];
  auto stage2 = [&](const unsigned short* pa, const unsigned short* pb){
    gload16(pa,         ldsA0);
    gload16(pa + 65536, ldsA1);
    gload16(pb,         ldsB0);
    gload16(pb + 65536, ldsB1);
  };

  if (blockIdx.x >= 512){
    // ---------------- GEMM1 filler ----------------
    const int gb = blockIdx.x - 512;
    const int row0 = (gb & 63) * 128, col0 = (gb >> 6) * 128;
    const unsigned short* pa = Xb  + (size_t)(row0 + wid*16 + srow) * 1024 + scol;
    const unsigned short* pb = gBt + (size_t)(col0 + wid*16 + srow) * 1024 + scol;
    f32x4 acc[4][4] = {};
    for (int k0 = 0; k0 < 1024; k0 += 32){
      __syncthreads();
      stage2(pa, pb);
      pa += 32; pb += 32;
      __syncthreads();
      bf16x8 af[4], bfr[4];
      #pragma unroll
      for (int m = 0; m < 4; m++) af[m]  = *(const bf16x8*)&As[wr*64 + m*16 + r16][kg*8];
      #pragma unroll
      for (int n = 0; n < 4; n++) bfr[n] = *(const bf16x8*)&Bs[wc*64 + n*16 + r16][kg*8];
      #pragma unroll
      for (int m = 0; m < 4; m++)
        #pragma unroll
        for (int n = 0; n < 4; n++)
          acc[m][n] = __builtin_amdgcn_mfma_f32_16x16x32_bf16(af[m], bfr[n], acc[m][n], 0, 0, 0);
    }
    #pragma unroll
    for (int m = 0; m < 4; m++){
      #pragma unroll
      for (int n = 0; n < 4; n++){
        const int gc = col0 + wc*64 + n*16 + r16;
        const float bv = gBias[gc];
        #pragma unroll
        for (int r = 0; r < 4; r++){
          const int gr = row0 + wr*64 + m*16 + kg*4 + r;
          gC[(size_t)gr * 2048 + gc] = f2bf(fmaxf(acc[m][n][r] + bv, 0.f));
        }
      }
    }
    return;
  }

  // ---------------- gram block ----------------
  const float INF = __builtin_inff();
  const int INFI = 0x7FFFFFFF;
  const int bi = blockIdx.x & 63;
  const int cl = blockIdx.x >> 6;          // 0..7
  const int row0 = bi * 128;
  const int ntt = (cl == 7) ? 5 : 4;
  const int selrow = tid & 127, half = tid >> 7, selc0 = half * 64;
  const int thrRI = thrI[row0 + selrow];

  const unsigned short* aB = Xb + (size_t)(row0 + wid*16 + srow) * 1024 + scol;

  int r0,r1,r2,r3,r4,r5,r6,r7,r8,r9,r10,r11,r12,r13,r14;
  r0=r1=r2=r3=r4=r5=r6=r7=r8=r9=r10=r11=r12=r13=r14=INFI;
  INS15(insR, r0,r1,r2,r3,r4,r5,r6,r7,r8,r9,r10,r11,r12,r13,r14);
  int c0,c1,c2,c3,c4,c5,c6,c7,c8,c9,c10,c11,c12,c13,c14;
  INS15(insC, c0,c1,c2,c3,c4,c5,c6,c7,c8,c9,c10,c11,c12,c13,c14);

  float xr[4][4];
  #pragma unroll
  for (int m = 0; m < 4; m++)
    #pragma unroll
    for (int r = 0; r < 4; r++)
      xr[m][r] = xsq[row0 + wr*64 + m*16 + kg*4 + r];

  // prologue: stage tile 0 panel 0
  stage2(aB, Xb + (size_t)(((bi + cl*4) & 63) * 128 + wid*16 + srow) * 1024 + scol);

  for (int tt = 0; tt < ntt; ++tt){
    const int d = cl * 4 + tt;               // 0..32
    const int bj = (bi + d) & 63;
    const int j0 = bj * 128;
    const unsigned short* bB  = Xb + (size_t)(j0 + wid*16 + srow) * 1024 + scol;
    const unsigned short* bBn = Xb + (size_t)(((bi + d + 1) & 63) * 128 + wid*16 + srow) * 1024 + scol;
    const unsigned short* pa = aB;
    const unsigned short* pb = bB;
    f32x4 acc[4][4] = {};
    for (int k0 = 0; k0 < 1024; k0 += 32){
      __syncthreads();                       // staged panel ready (vmcnt drain)
      bf16x8 af[4], bfr[4];
      #pragma unroll
      for (int m = 0; m < 4; m++) af[m]  = *(const bf16x8*)&As[wr*64 + m*16 + r16][kg*8];
      #pragma unroll
      for (int n = 0; n < 4; n++) bfr[n] = *(const bf16x8*)&Bs[wc*64 + n*16 + r16][kg*8];
      __syncthreads();                       // frag reads complete
      if (k0 + 32 < 1024){ pa += 32; pb += 32; stage2(pa, pb); }
      else if (tt + 1 < ntt) stage2(aB, bBn);
      #pragma unroll
      for (int m = 0; m < 4; m++)
        #pragma unroll
        for (int n = 0; n < 4; n++)
          acc[m][n] = __builtin_amdgcn_mfma_f32_16x16x32_bf16(af[m], bfr[n], acc[m][n], 0, 0, 0);
    }
    // d^2 tile -> bf16 LDS (diag -> +inf)
    float xc[4];
    #pragma unroll
    for (int n = 0; n < 4; n++) xc[n] = xsq[j0 + wc*64 + n*16 + r16];
    #pragma unroll
    for (int m = 0; m < 4; m++){
      #pragma unroll
      for (int n = 0; n < 4; n++){
        const int lc = wc*64 + n*16 + r16;
        #pragma unroll
        for (int r = 0; r < 4; r++){
          const int lr = wr*64 + m*16 + kg*4 + r;
          float v = xr[m][r] + xc[n] - 2.f * acc[m][n][r];
          if (row0 + lr == j0 + lc) v = INF;
          d2s[lr][lc] = f2bf(v);
        }
      }
    }
    lds_barrier();                           // d2s ready (prefetch stays in flight)

    // row-scan phase A: thr-passers -> private bucket (rare overflow: direct)
    {
      int cnt = 0;
      const int jg0 = j0 + selc0;
      #pragma unroll 4
      for (int cc = 0; cc < 64; cc += 2){
        unsigned pv = *(const unsigned*)&d2s[selrow][selc0 + cc];
        int p0 = (int)((pv << 16) | (unsigned)(jg0 + cc));
        int p1 = (int)((pv & 0xFFFF0000u) | (unsigned)(jg0 + cc + 1));
        if (p0 <= thrRI){
          if (cnt < 16){ bkt[cnt][tid] = (unsigned)p0; ++cnt; } else insR(p0);
        }
        if (p1 <= thrRI){
          if (cnt < 16){ bkt[cnt][tid] = (unsigned)p1; ++cnt; } else insR(p1);
        }
      }
      // phase B: drain bucket (wave cost = max-lane count, not 64 steps)
      for (int q = 0; q < cnt; ++q) insR((int)bkt[q][tid]);
    }

    // col-scan (rows of bj), d in [1..31]
    const bool doCol = (d >= 1) && (d <= 31);
    if (doCol){
      c0=c1=c2=c3=c4=c5=c6=c7=c8=c9=c10=c11=c12=c13=c14=INFI;
      const int thrCI = thrI[j0 + selrow];
      const int rbase = row0 + selc0;
      int cnt = 0;
      #pragma unroll 4
      for (int rr = 0; rr < 64; ++rr){
        unsigned v = d2s[selc0 + rr][selrow];
        int pk = (int)((v << 16) | (unsigned)(rbase + rr));
        if (pk <= thrCI){
          if (cnt < 16){ bkt[cnt][tid] = (unsigned)pk; ++cnt; } else insC(pk);
        }
      }
      for (int q = 0; q < cnt; ++q) insC((int)bkt[q][tid]);
      if (half){
        colL[selrow][0]=c0;  colL[selrow][1]=c1;  colL[selrow][2]=c2;
        colL[selrow][3]=c3;  colL[selrow][4]=c4;  colL[selrow][5]=c5;
        colL[selrow][6]=c6;  colL[selrow][7]=c7;  colL[selrow][8]=c8;
        colL[selrow][9]=c9;  colL[selrow][10]=c10; colL[selrow][11]=c11;
        colL[selrow][12]=c12; colL[selrow][13]=c13; colL[selrow][14]=c14;
      }
    }
    lds_barrier();                           // colL ready / d2s reads done
    if (doCol && !half){
      #pragma unroll 1
      for (int q = 0; q < 15; ++q){
        int v = colL[selrow][q];
        if (v >= c14) break;
        insC(v);
      }
      int* dst = topP + ((size_t)(j0 + selrow) * NLISTS + (8 + d - 1)) * 15;
      dst[0]=c0;  dst[1]=c1;  dst[2]=c2;  dst[3]=c3;  dst[4]=c4;
      dst[5]=c5;  dst[6]=c6;  dst[7]=c7;  dst[8]=c8;  dst[9]=c9;
      dst[10]=c10; dst[11]=c11; dst[12]=c12; dst[13]=c13; dst[14]=c14;
    }
  }
  // merge row-scan halves in LDS -> one list per row per chunk (slot cl)
  lds_barrier();
  if (half){
    colL[selrow][0]=r0;  colL[selrow][1]=r1;  colL[selrow][2]=r2;
    colL[selrow][3]=r3;  colL[selrow][4]=r4;  colL[selrow][5]=r5;
    colL[selrow][6]=r6;  colL[selrow][7]=r7;  colL[selrow][8]=r8;
    colL[selrow][9]=r9;  colL[selrow][10]=r10; colL[selrow][11]=r11;
    colL[selrow][12]=r12; colL[selrow][13]=r13; colL[selrow][14]=r14;
  }
  lds_barrier();
  if (!half){
    #pragma unroll 1
    for (int q = 0; q < 15; ++q){
      int v = colL[selrow][q];
      if (v >= r14) break;
      insR(v);
    }
    int* dst = topP + ((size_t)(row0 + selrow) * NLISTS + cl) * 15;
    dst[0]=r0;  dst[1]=r1;  dst[2]=r2;  dst[3]=r3;  dst[4]=r4;
    dst[5]=r5;  dst[6]=r6;  dst[7]=r7;  dst[8]=r8;  dst[9]=r9;
    dst[10]=r10; dst[11]=r11; dst[12]=r12; dst[13]=r13; dst[14]=r14;
  }
}

// merge 39 partial 15-lists (585 candidates, disjoint j) -> final 15 per row.
// Also per-block max of 15th-NN d2 (x_max) -> xpart[block].
__global__ __launch_bounds__(256) void merge_topk_k(const int* __restrict__ topP,
    int* __restrict__ knn, float* __restrict__ d2k, float* __restrict__ xpart)
{
  __shared__ float wmax[4];
  const int lane = threadIdx.x & 63, wid = threadIdx.x >> 6;
  const int row = blockIdx.x * 4 + wid;
  const int* tp = topP + (size_t)row * (NLISTS * 15);
  const int INFI = 0x7FFFFFFF;
  int c0 = tp[lane];
  int c1 = tp[lane + 64];
  int c2 = tp[lane + 128];
  int c3 = tp[lane + 192];
  int c4 = tp[lane + 256];
  int c5 = tp[lane + 320];
  int c6 = tp[lane + 384];
  int c7 = tp[lane + 448];
  int c8 = tp[lane + 512];
  int c9 = (lane < 9) ? tp[lane + 576] : INFI;
  float last = 0.f;
  for (int it = 0; it < 15; ++it){
    int m = min(min(min(c0, c1), min(c2, c3)), min(min(c4, c5), min(c6, c7)));
    m = min(m, min(c8, c9));
    #pragma unroll
    for (int o = 32; o; o >>= 1) m = min(m, __shfl_xor(m, o));
    if (!lane){
      knn[row * 15 + it] = m & 0xFFFF;
      float f = __uint_as_float((unsigned)m & 0xFFFF0000u);
      d2k[row * 15 + it] = f;
      last = f;
    }
    c0 = (c0 == m) ? INFI : c0;   c1 = (c1 == m) ? INFI : c1;
    c2 = (c2 == m) ? INFI : c2;   c3 = (c3 == m) ? INFI : c3;
    c4 = (c4 == m) ? INFI : c4;   c5 = (c5 == m) ? INFI : c5;
    c6 = (c6 == m) ? INFI : c6;   c7 = (c7 == m) ? INFI : c7;
    c8 = (c8 == m) ? INFI : c8;   c9 = (c9 == m) ? INFI : c9;
  }
  if (!lane) wmax[wid] = last;
  __syncthreads();
  if (!threadIdx.x)
    xpart[blockIdx.x] = fmaxf(fmaxf(wmax[0], wmax[1]), fmaxf(wmax[2], wmax[3]));
}

// ---------------------------------------------------------------------------
// Edge-based loss sums over the 122880 directed knn edges. For edge (i,j):
// mult = 1 + [i in knn[j]]; weight w = 2/mult. Equals the masked-pair mean.
__global__ __launch_bounds__(256) void pair_sums_k(
    const float* __restrict__ z, const int* __restrict__ knn,
    const float* __restrict__ d2k,
    float* __restrict__ zzP, float* __restrict__ zxP, float* __restrict__ xxP,
    float* __restrict__ zmP, float* __restrict__ cntP)
{
  __shared__ float red[4][5];
  const int lane = threadIdx.x & 63, wid = threadIdx.x >> 6;
  float szz = 0.f, szx = 0.f, sxx = 0.f, mz = 0.f, scnt = 0.f;
  for (int p = blockIdx.x * 4 + wid; p < 122880; p += gridDim.x * 4){
    const int i = p / 15;
    const int j = knn[p];
    const float dx2 = d2k[p];
    float dd = z[(size_t)i * 64 + lane] - z[(size_t)j * 64 + lane];
    float s = dd * dd;
    #pragma unroll
    for (int o = 32; o; o >>= 1) s += __shfl_xor(s, o);
    int kj = knn[j * 15 + min(lane, 14)];
    unsigned long long m2 = __ballot(lane < 15 && kj == i);
    const float w = m2 ? 1.f : 2.f;          // 2/mult
    float dz = sqrtf(s), dx = sqrtf(dx2);
    szz += w * s;
    szx += w * dz * dx;
    sxx += w * dx2;
    scnt += w;
    mz = fmaxf(mz, dz);
  }
  if (!lane){
    red[wid][0] = szz; red[wid][1] = szx; red[wid][2] = sxx;
    red[wid][3] = mz;  red[wid][4] = scnt;
  }
  __syncthreads();
  if (!threadIdx.x){
    float a = 0.f, b = 0.f, c = 0.f, m = 0.f, n = 0.f;
    #pragma unroll
    for (int w = 0; w < 4; w++){
      a += red[w][0]; b += red[w][1]; c += red[w][2];
      m = fmaxf(m, red[w][3]); n += red[w][4];
    }
    zzP[blockIdx.x] = a; zxP[blockIdx.x] = b; xxP[blockIdx.x] = c;
    zmP[blockIdx.x] = m; cntP[blockIdx.x] = n;
  }
}

// single block: reduce all partials, compute losses, write outputs.
__global__ __launch_bounds__(256) void final_reduce_k(
    const float* __restrict__ recPart, const float* __restrict__ xpart,
    const float* __restrict__ zzP, const float* __restrict__ zxP,
    const float* __restrict__ xxP, const float* __restrict__ zmP,
    const float* __restrict__ cntP, float* __restrict__ out)
{
  __shared__ float rd[4][7];
  const int t = threadIdx.x, lane = t & 63, wid = t >> 6;
  float rec = 0.f, xm = 0.f, zz = 0.f, zx = 0.f, xx = 0.f, zm = 0.f, cnt = 0.f;
  for (int i = t; i < 1024; i += 256) rec += recPart[i];
  for (int i = t; i < 2048; i += 256) xm = fmaxf(xm, xpart[i]);
  for (int i = t; i < 1920; i += 256){
    zz += zzP[i]; zx += zxP[i]; xx += xxP[i]; cnt += cntP[i];
    zm = fmaxf(zm, zmP[i]);
  }
  #pragma unroll
  for (int o = 32; o; o >>= 1){
    rec += __shfl_xor(rec, o); zz += __shfl_xor(zz, o);
    zx  += __shfl_xor(zx, o);  xx += __shfl_xor(xx, o);
    cnt += __shfl_xor(cnt, o);
    xm = fmaxf(xm, __shfl_xor(xm, o));
    zm = fmaxf(zm, __shfl_xor(zm, o));
  }
  if (!lane){
    rd[wid][0]=rec; rd[wid][1]=zz; rd[wid][2]=zx; rd[wid][3]=xx;
    rd[wid][4]=xm;  rd[wid][5]=zm; rd[wid][6]=cnt;
  }
  __syncthreads();
  if (!t){
    rec = rd[0][0]+rd[1][0]+rd[2][0]+rd[3][0];
    zz  = rd[0][1]+rd[1][1]+rd[2][1]+rd[3][1];
    zx  = rd[0][2]+rd[1][2]+rd[2][2]+rd[3][2];
    xx  = rd[0][3]+rd[1][3]+rd[2][3]+rd[3][3];
    xm  = fmaxf(fmaxf(rd[0][4],rd[1][4]), fmaxf(rd[2][4],rd[3][4]));
    zm  = fmaxf(fmaxf(rd[0][5],rd[1][5]), fmaxf(rd[2][5],rd[3][5]));
    cnt = rd[0][6]+rd[1][6]+rd[2][6]+rd[3][6];
    rec *= 1.0f / (8192.0f * 1024.0f);
    float xmax = sqrtf(xm);
    float rx = 1.0f / (xmax + 1e-8f), rz = 1.0f / (zm + 1e-8f);
    float knn = (zz * rz * rz - 2.0f * zx * rz * rx + xx * rx * rx) / cnt;
    out[0] = rec + knn;                 // total
    out[1 + 8192 * 64]     = rec;       // rec_loss
    out[1 + 8192 * 64 + 1] = knn;       // knn_loss
  }
}

// ===========================================================================
extern "C" void kernel_launch(void* const* d_in, const int* in_sizes, int n_in,
                              void* d_out, int out_size, void* d_ws, size_t ws_size,
                              hipStream_t stream)
{
  (void)in_sizes; (void)n_in; (void)out_size;
  const float* x    = (const float*)d_in[0];
  const float* w_e0 = (const float*)d_in[1];  const float* b_e0 = (const float*)d_in[2];
  const float* w_e1 = (const float*)d_in[3];  const float* b_e1 = (const float*)d_in[4];
  const float* w_e2 = (const float*)d_in[5];  const float* b_e2 = (const float*)d_in[6];
  const float* w_d0 = (const float*)d_in[7];  const float* b_d0 = (const float*)d_in[8];
  const float* w_d1 = (const float*)d_in[9];  const float* b_d1 = (const float*)d_in[10];
  const float* w_d2 = (const float*)d_in[11]; const float* b_d2 = (const float*)d_in[12];
  float* out = (float*)d_out;

  char* ws = (char*)d_ws;
  size_t off = 0;
  auto alloc = [&](size_t bytes) -> void* {
    void* p = ws + off;
    off += (bytes + 255) & ~(size_t)255;
    return p;
  };
  unsigned short* xb   = (unsigned short*)alloc(8192ull * 1024 * 2);
  unsigned short* wte0 = (unsigned short*)alloc(2048ull * 1024 * 2);
  unsigned short* wte1 = (unsigned short*)alloc(512ull  * 2048 * 2);
  unsigned short* wte2 = (unsigned short*)alloc(64ull   * 512  * 2);
  unsigned short* wtd0 = (unsigned short*)alloc(512ull  * 64   * 2);
  unsigned short* wtd1 = (unsigned short*)alloc(2048ull * 512  * 2);
  unsigned short* wtd2 = (unsigned short*)alloc(1024ull * 2048 * 2);
  unsigned short* bufA = (unsigned short*)alloc(8192ull * 2048 * 2);   // H1 / H4
  unsigned short* bufB = (unsigned short*)alloc(8192ull * 512  * 2);   // H2 / H3
  unsigned short* zb   = (unsigned short*)alloc(8192ull * 64   * 2);
  int*   topP   = (int*)  alloc(8192ull * NLISTS * 15 * 4);            // 19.2MB
  float* xsq    = (float*)alloc(8192 * 4);
  int*   thrI   = (int*)  alloc(8192 * 4);
  int*   knn    = (int*)  alloc(8192ull * 15 * 4);
  float* d2k    = (float*)alloc(8192ull * 15 * 4);
  float* xpart  = (float*)alloc(2048 * 4);
  float* zzP    = (float*)alloc(1920 * 4);
  float* zxP    = (float*)alloc(1920 * 4);
  float* xxP    = (float*)alloc(1920 * 4);
  float* zmP    = (float*)alloc(1920 * 4);
  float* cntP   = (float*)alloc(1920 * 4);
  float* recPart= (float*)alloc(1024 * 4);
  if (off > ws_size) return;   // fail loudly (poisoned output) rather than corrupt

  // --- conversions + weight transposes (one launch) ---
  cvtT_k<<<8256, 256, 0, stream>>>(x, xb, xsq,
      w_e0, w_e1, w_e2, w_d0, w_d1, w_d2, wte0, wte1, wte2, wtd0, wtd1, wtd2);

  // --- per-row selection thresholds (diag-block 15th-NN) ---
  thr_k<<<64, 256, 0, stream>>>(xb, xsq, thrI);

  // --- fused: gram+top15 (0..511) + GEMM1 tail-filler (512..1535) ---
  gram_topk_k<<<1536, 256, 0, stream>>>(xb, xsq, thrI, topP, wte0, b_e0, bufA);
  merge_topk_k<<<2048, 256, 0, stream>>>(topP, knn, d2k, xpart);

  // --- rest of MLP ---
  gemm_bt<128, 64,2,2,true ,0><<<dim3(64, 8), 256, 0, stream>>>(bufA, wte1, b_e1, 8192,  512, 2048, bufB, nullptr, nullptr, nullptr);
  gemm_bt< 32, 64,2,2,false,1><<<dim3(256,1), 256, 0, stream>>>(bufB, wte2, b_e2, 8192,   64,  512, zb,   out + 1, nullptr, nullptr);
  gemm_bt<128, 64,2,2,true ,0><<<dim3(64, 8), 256, 0, stream>>>(zb,   wtd0, b_d0, 8192,  512,   64, bufB, nullptr, nullptr, nullptr);
  gemm_bt<128,128,2,2,true ,0><<<dim3(64,16), 256, 0, stream>>>(bufB, wtd1, b_d1, 8192, 2048,  512, bufA, nullptr, nullptr, nullptr);
  gemm_bt< 64,128,2,2,false,2><<<dim3(128,8), 256, 0, stream>>>(bufA, wtd2, b_d2, 8192, 1024, 2048, nullptr, nullptr, x, recPart);

  // --- KNN loss tail (edge-based) ---
  pair_sums_k<<<1920, 256, 0, stream>>>(out + 1, knn, d2k, zzP, zxP, xxP, zmP, cntP);
  final_reduce_k<<<1, 256, 0, stream>>>(recPart, xpart, zzP, zxP, xxP, zmP, cntP, out);
}